// Round 1
// baseline (388.188 us; speedup 1.0000x reference)
//
#include <hip/hip_runtime.h>
#include <stdint.h>

// Problem constants: B=2, S=2048, D=1024, H=16, HD=64
#define S_LEN 2048
#define D_DIM 1024
#define N_HEAD 16

typedef unsigned short u16;
typedef __attribute__((ext_vector_type(4))) float f32x4;
typedef __attribute__((ext_vector_type(8))) short bf16x8;   // 8 bf16 = 4 VGPRs (MFMA A/B frag)
typedef __attribute__((ext_vector_type(4))) unsigned short u16x4;
typedef __attribute__((ext_vector_type(4))) float flt4;

#define MFMA16(a, b, c) __builtin_amdgcn_mfma_f32_16x16x32_bf16((a), (b), (c), 0, 0, 0)

__device__ __forceinline__ u16 f32_bf16(float f) {
    union { float f; uint32_t u; } x;
    x.f = f;
    uint32_t r = (x.u + 0x7FFFu + ((x.u >> 16) & 1u)) >> 16;  // RNE
    return (u16)r;
}

// async global->LDS, 16B per lane. LDS dest = wave-uniform base + lane*16.
__device__ __forceinline__ void gload_lds16(const void* g, void* l) {
    __builtin_amdgcn_global_load_lds(
        (const __attribute__((address_space(1))) unsigned int*)(uintptr_t)g,
        (__attribute__((address_space(3))) unsigned int*)(uint32_t)(uintptr_t)l,
        16, 0, 0);
}

// ---------------- conversion kernels ----------------

__global__ __launch_bounds__(256) void cvt_bf16_kernel(const float* __restrict__ in,
                                                       u16* __restrict__ out, int n) {
    int i = (blockIdx.x * 256 + threadIdx.x) * 4;
    if (i < n) {
        flt4 v = *(const flt4*)(in + i);
        u16x4 u;
        u[0] = f32_bf16(v[0]); u[1] = f32_bf16(v[1]);
        u[2] = f32_bf16(v[2]); u[3] = f32_bf16(v[3]);
        *(u16x4*)(out + i) = u;
    }
}

// in: [R][C] f32 row-major  ->  out: [C][R] bf16 row-major (i.e. in^T)
__global__ __launch_bounds__(256) void transpose_cvt_kernel(const float* __restrict__ in,
                                                            u16* __restrict__ out,
                                                            int R, int C) {
    __shared__ float tile[32][33];
    int tc = blockIdx.x * 32, tr = blockIdx.y * 32;
    int lx = threadIdx.x & 31, ly = threadIdx.x >> 5;  // 32 x 8
#pragma unroll
    for (int i = 0; i < 32; i += 8)
        tile[ly + i][lx] = in[(size_t)(tr + ly + i) * C + tc + lx];
    __syncthreads();
#pragma unroll
    for (int i = 0; i < 32; i += 8)
        out[(size_t)(tc + ly + i) * R + tr + lx] = f32_bf16(tile[lx][ly + i]);
}

// ---------------- GEMM: C[M,N] = A[M,K] @ Bt[N,K]^T  (bf16 in, f32 acc) ----------------
// 128x128 tile, BK=32, 4 waves (2x2 of 64x64), 16x16x32 bf16 MFMA, global_load_lds staging.
// MODE 0: outF[r*N+c] = acc + bias[c]                  (f32, final projection)
// MODE 1: scatter to Q [B,H,S,64], K [B,H,S,64], V^T [B,H,64,S]  (bf16, qkv)

template <int MODE>
__global__ __launch_bounds__(256)
void gemm_bt_kernel(const u16* __restrict__ A, const u16* __restrict__ Bt,
                    const float* __restrict__ bias,
                    float* __restrict__ outF,
                    u16* __restrict__ qo, u16* __restrict__ ko, u16* __restrict__ vto,
                    int M, int N, int K) {
    __shared__ u16 As[128 * 32];
    __shared__ u16 Bs[128 * 32];
    const int tid = threadIdx.x;
    const int w = tid >> 6, lane = tid & 63;
    const int lr = lane & 15, lg = lane >> 4;
    const int bm = blockIdx.y * 128, bn = blockIdx.x * 128;
    const int wr = w >> 1, wc = w & 1;

    f32x4 acc[4][4];
#pragma unroll
    for (int m = 0; m < 4; m++)
#pragma unroll
        for (int n = 0; n < 4; n++) acc[m][n] = (f32x4){0.f, 0.f, 0.f, 0.f};

    // staging: inst i covers rows i*64 + (tid>>2), cols (tid&3)*8 .. +8
    const u16* Abase = A + (size_t)(bm + (tid >> 2)) * K + (tid & 3) * 8;
    const u16* Bbase = Bt + (size_t)(bn + (tid >> 2)) * K + (tid & 3) * 8;
    u16* AsW = As + w * 512;  // wave-uniform LDS dest base
    u16* BsW = Bs + w * 512;

    for (int kt = 0; kt < K; kt += 32) {
        gload_lds16(Abase + kt, AsW);
        gload_lds16(Abase + kt + (size_t)64 * K, AsW + 2048);
        gload_lds16(Bbase + kt, BsW);
        gload_lds16(Bbase + kt + (size_t)64 * K, BsW + 2048);
        __syncthreads();  // drains vmcnt -> staged data visible

        bf16x8 a[4], b[4];
        const bf16x8* Av = (const bf16x8*)As;
        const bf16x8* Bv = (const bf16x8*)Bs;
#pragma unroll
        for (int m = 0; m < 4; m++) a[m] = Av[(wr * 64 + m * 16 + lr) * 4 + lg];
#pragma unroll
        for (int n = 0; n < 4; n++) b[n] = Bv[(wc * 64 + n * 16 + lr) * 4 + lg];
#pragma unroll
        for (int m = 0; m < 4; m++)
#pragma unroll
            for (int n = 0; n < 4; n++)
                acc[m][n] = MFMA16(a[m], b[n], acc[m][n]);
        __syncthreads();  // all reads done before next-step staging overwrites
    }

    const int rowb = bm + wr * 64, colb = bn + wc * 64;
    if (MODE == 0) {
#pragma unroll
        for (int m = 0; m < 4; m++)
#pragma unroll
            for (int j = 0; j < 4; j++) {
                int r = rowb + m * 16 + lg * 4 + j;
                size_t base = (size_t)r * N;
#pragma unroll
                for (int n = 0; n < 4; n++) {
                    int c = colb + n * 16 + lr;
                    outF[base + c] = acc[m][n][j] + bias[c];
                }
            }
    } else {
#pragma unroll
        for (int m = 0; m < 4; m++)
#pragma unroll
            for (int j = 0; j < 4; j++) {
                int r = rowb + m * 16 + lg * 4 + j;     // 0..M-1 (= b*S + s)
                int bb = r >> 11, s = r & (S_LEN - 1);
#pragma unroll
                for (int n = 0; n < 4; n++) {
                    int c = colb + n * 16 + lr;          // 0..3D-1
                    float v = acc[m][n][j] + bias[c];
                    u16 bv = f32_bf16(v);
                    int part = c >> 10, cc = c & (D_DIM - 1);
                    int h = cc >> 6, d = cc & 63;
                    size_t bh = (size_t)(bb * N_HEAD + h);
                    if (part == 0)      qo[(bh * S_LEN + s) * 64 + d] = bv;
                    else if (part == 1) ko[(bh * S_LEN + s) * 64 + d] = bv;
                    else                vto[(bh * 64 + d) * S_LEN + s] = bv;
                }
            }
    }
}

// ---------------- flash attention (causal) ----------------
// grid (S/64, B*H), 256 thr = 4 waves; wave w owns q-rows [qb*64+w*16, +16).
// KV tiles of 32; no cross-wave barriers (per-wave LDS P-buffer only).

__global__ __launch_bounds__(256)
void flash_attn_kernel(const u16* __restrict__ Qg, const u16* __restrict__ Kg,
                       const u16* __restrict__ Vt, u16* __restrict__ Og) {
    const int bh = blockIdx.y;
    const int qb = blockIdx.x;
    const int tid = threadIdx.x, w = tid >> 6, lane = tid & 63;
    const int lr = lane & 15, lg = lane >> 4;
    const int qw = qb * 64 + w * 16;

    const u16* Qh = Qg + (size_t)bh * S_LEN * 64;
    const u16* Kh = Kg + (size_t)bh * S_LEN * 64;
    const u16* Vh = Vt + (size_t)bh * 64 * S_LEN;

    __shared__ __align__(16) u16 plds[4][16 * 48];  // per-wave P buffer, stride 48 (96B)
    u16* pw = plds[w];

    // Q fragments (A-frag: row = lr, k = lg*8+j), HD=64 -> two 32-wide chunks
    bf16x8 qa0 = *(const bf16x8*)(Qh + (size_t)(qw + lr) * 64 + lg * 8);
    bf16x8 qa1 = *(const bf16x8*)(Qh + (size_t)(qw + lr) * 64 + 32 + lg * 8);

    f32x4 o[4];
#pragma unroll
    for (int n = 0; n < 4; n++) o[n] = (f32x4){0.f, 0.f, 0.f, 0.f};
    float mrow[4], lrow[4];
#pragma unroll
    for (int j = 0; j < 4; j++) { mrow[j] = -1e30f; lrow[j] = 0.f; }

    const int nkv = (qw + 47) >> 5;  // causal: cover kv <= qw+15
    for (int t = 0; t < nkv; ++t) {
        const int kv0 = t * 32;
        // S tile [16q, 32kv]: 2 col-chunks x 2 d-chunks
        f32x4 s0 = (f32x4){0.f, 0.f, 0.f, 0.f};
        f32x4 s1 = (f32x4){0.f, 0.f, 0.f, 0.f};
        bf16x8 kb;
        kb = *(const bf16x8*)(Kh + (size_t)(kv0 + lr) * 64 + lg * 8);
        s0 = MFMA16(qa0, kb, s0);
        kb = *(const bf16x8*)(Kh + (size_t)(kv0 + lr) * 64 + 32 + lg * 8);
        s0 = MFMA16(qa1, kb, s0);
        kb = *(const bf16x8*)(Kh + (size_t)(kv0 + 16 + lr) * 64 + lg * 8);
        s1 = MFMA16(qa0, kb, s1);
        kb = *(const bf16x8*)(Kh + (size_t)(kv0 + 16 + lr) * 64 + 32 + lg * 8);
        s1 = MFMA16(qa1, kb, s1);

        // scale + causal mask (C layout: row = lg*4+j, col = lr / 16+lr)
        float p0[4], p1[4], mx[4];
#pragma unroll
        for (int j = 0; j < 4; j++) {
            int row = qw + lg * 4 + j;
            float v0 = s0[j] * 0.125f;
            float v1 = s1[j] * 0.125f;
            if (kv0 + lr > row)      v0 = -1e30f;
            if (kv0 + 16 + lr > row) v1 = -1e30f;
            p0[j] = v0; p1[j] = v1;
            mx[j] = fmaxf(v0, v1);
        }
        // row max across the 16 lanes of the lg-group
#pragma unroll
        for (int off = 1; off < 16; off <<= 1)
#pragma unroll
            for (int j = 0; j < 4; j++) mx[j] = fmaxf(mx[j], __shfl_xor(mx[j], off));

        float corr[4], rs[4];
#pragma unroll
        for (int j = 0; j < 4; j++) {
            float mn = fmaxf(mrow[j], mx[j]);
            corr[j] = __expf(mrow[j] - mn);
            mrow[j] = mn;
            float e0 = __expf(p0[j] - mn);
            float e1 = __expf(p1[j] - mn);
            p0[j] = e0; p1[j] = e1;
            rs[j] = e0 + e1;
        }
#pragma unroll
        for (int off = 1; off < 16; off <<= 1)
#pragma unroll
            for (int j = 0; j < 4; j++) rs[j] += __shfl_xor(rs[j], off);
#pragma unroll
        for (int j = 0; j < 4; j++) lrow[j] = lrow[j] * corr[j] + rs[j];
#pragma unroll
        for (int n = 0; n < 4; n++)
#pragma unroll
            for (int j = 0; j < 4; j++) o[n][j] *= corr[j];

        // P (accum layout) -> LDS -> A-frag layout
#pragma unroll
        for (int j = 0; j < 4; j++) {
            pw[(lg * 4 + j) * 48 + lr] = f32_bf16(p0[j]);
            pw[(lg * 4 + j) * 48 + 16 + lr] = f32_bf16(p1[j]);
        }
        asm volatile("s_waitcnt lgkmcnt(0)" ::: "memory");
        bf16x8 pa = *(const bf16x8*)(pw + lr * 48 + lg * 8);

        // PV: O[16,64] += P[16,32] @ V[32,64]; B-frag from V^T contiguous
#pragma unroll
        for (int n = 0; n < 4; n++) {
            bf16x8 vb = *(const bf16x8*)(Vh + (size_t)(n * 16 + lr) * S_LEN + kv0 + lg * 8);
            o[n] = MFMA16(pa, vb, o[n]);
        }
    }

    // epilogue: normalize and write attn output as [B,S,H*64] bf16
    const int b = bh >> 4, h = bh & 15;
#pragma unroll
    for (int j = 0; j < 4; j++) {
        float inv = 1.f / lrow[j];
        size_t orow = (size_t)(b * S_LEN + qw + lg * 4 + j);
#pragma unroll
        for (int n = 0; n < 4; n++)
            Og[orow * D_DIM + h * 64 + n * 16 + lr] = f32_bf16(o[n][j] * inv);
    }
}

// ---------------- launch ----------------

extern "C" void kernel_launch(void* const* d_in, const int* in_sizes, int n_in,
                              void* d_out, int out_size, void* d_ws, size_t ws_size,
                              hipStream_t stream) {
    const float* x  = (const float*)d_in[0];   // [2,2048,1024]
    const float* w1 = (const float*)d_in[1];   // [1024,3072]
    const float* b1 = (const float*)d_in[2];   // [3072]
    const float* w2 = (const float*)d_in[3];   // [1024,1024]
    const float* b2 = (const float*)d_in[4];   // [1024]
    float* out = (float*)d_out;                // [2,2048,1024] f32

    // workspace partition (bf16 elements), total 48 MB
    u16* ws  = (u16*)d_ws;
    u16* xb  = ws;                       // 4096*1024
    u16* w1t = xb  + 4096 * 1024;        // 3072*1024  (= c_attn_w^T)
    u16* w2t = w1t + 3072 * 1024;        // 1024*1024  (= c_proj_w^T)
    u16* q   = w2t + 1024 * 1024;        // [B,H,S,64] = 4194304
    u16* k   = q   + 4194304;            // [B,H,S,64]
    u16* vt  = k   + 4194304;            // [B,H,64,S]
    u16* x2  = vt  + 4194304;            // attn out bf16 [4096,1024]

    cvt_bf16_kernel<<<dim3(4096), dim3(256), 0, stream>>>(x, xb, 4096 * 1024);
    transpose_cvt_kernel<<<dim3(3072 / 32, 1024 / 32), dim3(256), 0, stream>>>(w1, w1t, 1024, 3072);
    transpose_cvt_kernel<<<dim3(1024 / 32, 1024 / 32), dim3(256), 0, stream>>>(w2, w2t, 1024, 1024);

    gemm_bt_kernel<1><<<dim3(3072 / 128, 4096 / 128), dim3(256), 0, stream>>>(
        xb, w1t, b1, nullptr, q, k, vt, 4096, 3072, 1024);

    flash_attn_kernel<<<dim3(S_LEN / 64, 32), dim3(256), 0, stream>>>(q, k, vt, x2);

    gemm_bt_kernel<0><<<dim3(1024 / 128, 4096 / 128), dim3(256), 0, stream>>>(
        x2, w2t, b2, out, nullptr, nullptr, nullptr, 4096, 1024, 1024);
}

// Round 3
// 235.172 us; speedup vs baseline: 1.6507x; 1.6507x over previous
//
#include <hip/hip_runtime.h>
#include <hip/hip_bf16.h>
#include <stdint.h>

// Problem constants: B=2, S=2048, D=1024, H=16, HD=64
#define S_LEN 2048
#define D_DIM 1024
#define N_HEAD 16

typedef unsigned short u16;
typedef __attribute__((ext_vector_type(4))) float f32x4;
typedef __attribute__((ext_vector_type(16))) float f32x16;
typedef __attribute__((ext_vector_type(8))) short bf16x8;   // 8 bf16 = 4 VGPRs (MFMA A/B frag)
typedef __attribute__((ext_vector_type(4))) unsigned short u16x4;
typedef __attribute__((ext_vector_type(4))) float flt4;

#define MFMA16(a, b, c) __builtin_amdgcn_mfma_f32_16x16x32_bf16((a), (b), (c), 0, 0, 0)
#define MFMA32(a, b, c) __builtin_amdgcn_mfma_f32_32x32x16_bf16((a), (b), (c), 0, 0, 0)

__device__ __forceinline__ u16 f32_bf16(float f) {
    union { float f; uint32_t u; } x;
    x.f = f;
    uint32_t r = (x.u + 0x7FFFu + ((x.u >> 16) & 1u)) >> 16;  // RNE
    return (u16)r;
}

__device__ __forceinline__ uint32_t pack2(float a, float b) {
    __hip_bfloat162 h = __float22bfloat162_rn(float2{a, b});
    return *(uint32_t*)&h;
}

// async global->LDS, 16B per lane. LDS dest = wave-uniform base + lane*16.
__device__ __forceinline__ void gload_lds16(const void* g, void* l) {
    __builtin_amdgcn_global_load_lds(
        (const __attribute__((address_space(1))) unsigned int*)(uintptr_t)g,
        (__attribute__((address_space(3))) unsigned int*)(uint32_t)(uintptr_t)l,
        16, 0, 0);
}

// ---------------- conversion kernels ----------------

__global__ __launch_bounds__(256) void cvt_bf16_kernel(const float* __restrict__ in,
                                                       u16* __restrict__ out, int n) {
    int i = (blockIdx.x * 256 + threadIdx.x) * 4;
    if (i < n) {
        flt4 v = *(const flt4*)(in + i);
        u16x4 u;
        u[0] = f32_bf16(v[0]); u[1] = f32_bf16(v[1]);
        u[2] = f32_bf16(v[2]); u[3] = f32_bf16(v[3]);
        *(u16x4*)(out + i) = u;
    }
}

// in: [R][C] f32 row-major  ->  out: [C][R] bf16 row-major (i.e. in^T)
__global__ __launch_bounds__(256) void transpose_cvt_kernel(const float* __restrict__ in,
                                                            u16* __restrict__ out,
                                                            int R, int C) {
    __shared__ float tile[32][33];
    int tc = blockIdx.x * 32, tr = blockIdx.y * 32;
    int lx = threadIdx.x & 31, ly = threadIdx.x >> 5;  // 32 x 8
#pragma unroll
    for (int i = 0; i < 32; i += 8)
        tile[ly + i][lx] = in[(size_t)(tr + ly + i) * C + tc + lx];
    __syncthreads();
#pragma unroll
    for (int i = 0; i < 32; i += 8)
        out[(size_t)(tc + ly + i) * R + tr + lx] = f32_bf16(tile[lx][ly + i]);
}

// ---------------- GEMM: C[M,N] = A[M,K] @ Bt[N,K]^T  (bf16 in, f32 acc) ----------------
// 128x128 tile, BK=32, 4 waves (2x2 of 64x64), 16x16x32 bf16 MFMA, global_load_lds staging.
// MODE 0: outF[r*N+c] = acc + bias[c]                  (f32, final projection)
// MODE 1: scatter to Q [B,H,S,64] (x0.125), K [B,H,S,64], V^T [B,H,64,S]  (bf16, qkv)

template <int MODE>
__global__ __launch_bounds__(256)
void gemm_bt_kernel(const u16* __restrict__ A, const u16* __restrict__ Bt,
                    const float* __restrict__ bias,
                    float* __restrict__ outF,
                    u16* __restrict__ qo, u16* __restrict__ ko, u16* __restrict__ vto,
                    int M, int N, int K) {
    __shared__ u16 As[128 * 32];
    __shared__ u16 Bs[128 * 32];
    const int tid = threadIdx.x;
    const int w = tid >> 6, lane = tid & 63;
    const int lr = lane & 15, lg = lane >> 4;
    const int bm = blockIdx.y * 128, bn = blockIdx.x * 128;
    const int wr = w >> 1, wc = w & 1;

    f32x4 acc[4][4];
#pragma unroll
    for (int m = 0; m < 4; m++)
#pragma unroll
        for (int n = 0; n < 4; n++) acc[m][n] = (f32x4){0.f, 0.f, 0.f, 0.f};

    const u16* Abase = A + (size_t)(bm + (tid >> 2)) * K + (tid & 3) * 8;
    const u16* Bbase = Bt + (size_t)(bn + (tid >> 2)) * K + (tid & 3) * 8;
    u16* AsW = As + w * 512;
    u16* BsW = Bs + w * 512;

    for (int kt = 0; kt < K; kt += 32) {
        gload_lds16(Abase + kt, AsW);
        gload_lds16(Abase + kt + (size_t)64 * K, AsW + 2048);
        gload_lds16(Bbase + kt, BsW);
        gload_lds16(Bbase + kt + (size_t)64 * K, BsW + 2048);
        __syncthreads();

        bf16x8 a[4], b[4];
        const bf16x8* Av = (const bf16x8*)As;
        const bf16x8* Bv = (const bf16x8*)Bs;
#pragma unroll
        for (int m = 0; m < 4; m++) a[m] = Av[(wr * 64 + m * 16 + lr) * 4 + lg];
#pragma unroll
        for (int n = 0; n < 4; n++) b[n] = Bv[(wc * 64 + n * 16 + lr) * 4 + lg];
#pragma unroll
        for (int m = 0; m < 4; m++)
#pragma unroll
            for (int n = 0; n < 4; n++)
                acc[m][n] = MFMA16(a[m], b[n], acc[m][n]);
        __syncthreads();
    }

    const int rowb = bm + wr * 64, colb = bn + wc * 64;
    if (MODE == 0) {
#pragma unroll
        for (int m = 0; m < 4; m++)
#pragma unroll
            for (int j = 0; j < 4; j++) {
                int r = rowb + m * 16 + lg * 4 + j;
                size_t base = (size_t)r * N;
#pragma unroll
                for (int n = 0; n < 4; n++) {
                    int c = colb + n * 16 + lr;
                    outF[base + c] = acc[m][n][j] + bias[c];
                }
            }
    } else {
#pragma unroll
        for (int m = 0; m < 4; m++)
#pragma unroll
            for (int j = 0; j < 4; j++) {
                int r = rowb + m * 16 + lg * 4 + j;     // = b*S + s
                int bb = r >> 11, s = r & (S_LEN - 1);
#pragma unroll
                for (int n = 0; n < 4; n++) {
                    int c = colb + n * 16 + lr;          // 0..3D-1
                    float v = acc[m][n][j] + bias[c];
                    int part = c >> 10, cc = c & (D_DIM - 1);
                    if (part == 0) v *= 0.125f;          // fold 1/sqrt(64) into Q
                    u16 bv = f32_bf16(v);
                    int h = cc >> 6, d = cc & 63;
                    size_t bh = (size_t)(bb * N_HEAD + h);
                    if (part == 0)      qo[(bh * S_LEN + s) * 64 + d] = bv;
                    else if (part == 1) ko[(bh * S_LEN + s) * 64 + d] = bv;
                    else                vto[(bh * 64 + d) * S_LEN + s] = bv;
                }
            }
    }
}

// ---------------- flash attention (causal), 32x32x16 MFMA, swapped QK^T ----------------
// 512 blocks x 4 waves. Wave w of block p handles q-tile {p, 31-p, 32+p, 63-p}[w]
// (constant work per block -> no causal tail imbalance). Head chosen so all 16
// blocks of a head land on one XCD (id%8) -> K/V stays in that XCD's L2.
// Per wave: 32 q-rows; kv tiles of 32; K/V register double-buffered; softmax in-lane
// (S^T layout: lane = q-column); P via swizzled+padded LDS roundtrip (stride 40).

#define PSTRIDE 40   // u16 units; 80B rows -> bank stride 20, gcd(20,32)=4 (conflict ~2-way)

__global__ __launch_bounds__(256)
void flash_attn_kernel(const u16* __restrict__ Qg, const u16* __restrict__ Kg,
                       const u16* __restrict__ Vt, u16* __restrict__ Og) {
    const int id = blockIdx.x;
    const int xcd = id & 7, slot = id >> 3;      // slot 0..63
    const int bh = xcd * 4 + (slot & 3);         // 4 heads per XCD (2MB KV < 4MB L2)
    const int p  = slot >> 2;                    // 0..15
    const int w = threadIdx.x >> 6, lane = threadIdx.x & 63;
    const int qt = (w == 0) ? p : (w == 1) ? 31 - p : (w == 2) ? 32 + p : 63 - p;
    const int qbase = qt * 32;
    const int ql = lane & 31, hi = lane >> 5;
    const int swz = (ql & 3) << 3;               // XOR-swizzle (u16 units) for P buffer

    const u16* Qh = Qg + (size_t)bh * S_LEN * 64;
    const u16* Kh = Kg + (size_t)bh * S_LEN * 64;
    const u16* Vh = Vt + (size_t)bh * 64 * S_LEN;

    __shared__ __align__(16) u16 plds[4][32 * PSTRIDE];   // per-wave P buffer
    u16* pw = plds[w];

    // Q B-frag (col=q=ql, k=d): 4 chunks of K=16
    bf16x8 qf[4];
#pragma unroll
    for (int c = 0; c < 4; c++)
        qf[c] = *(const bf16x8*)(Qh + (size_t)(qbase + ql) * 64 + c * 16 + hi * 8);

    f32x16 ot0 = {}, ot1 = {};   // O^T accum: col=q, rows d 0..31 / 32..63
    float m = -1e30f, l = 0.f;

    // prefetch tile 0: K A-frag rows kv=ql, k=d; V^T A-frag rows d, k=kv
    bf16x8 kn[4], vn[4];
#pragma unroll
    for (int c = 0; c < 4; c++)
        kn[c] = *(const bf16x8*)(Kh + (size_t)ql * 64 + c * 16 + hi * 8);
#pragma unroll
    for (int u = 0; u < 4; u++)
        vn[u] = *(const bf16x8*)(Vh + (size_t)((u >> 1) * 32 + ql) * S_LEN + (u & 1) * 16 + hi * 8);

    for (int t = 0; t <= qt; ++t) {
        bf16x8 ka[4] = {kn[0], kn[1], kn[2], kn[3]};
        bf16x8 va[4] = {vn[0], vn[1], vn[2], vn[3]};
        if (t < qt) {   // issue next-tile loads now; latency hides under compute
            const size_t kvn = (size_t)(t + 1) * 32;
#pragma unroll
            for (int c = 0; c < 4; c++)
                kn[c] = *(const bf16x8*)(Kh + (kvn + ql) * 64 + c * 16 + hi * 8);
#pragma unroll
            for (int u = 0; u < 4; u++)
                vn[u] = *(const bf16x8*)(Vh + (size_t)((u >> 1) * 32 + ql) * S_LEN + kvn + (u & 1) * 16 + hi * 8);
        }

        // S^T[kv][q] = K·Q (Q pre-scaled by 0.125 in GEMM1): lane holds 16 kv for q=ql
        f32x16 st = {};
#pragma unroll
        for (int c = 0; c < 4; c++) st = MFMA32(ka[c], qf[c], st);

        float s[16];
#pragma unroll
        for (int r = 0; r < 16; r++) s[r] = st[r];
        if (t == qt) {  // only the diagonal tile needs the causal mask
#pragma unroll
            for (int r = 0; r < 16; r++) {
                int kvl = ((r & 3) + 8 * (r >> 2)) + 4 * hi;
                if (kvl > ql) s[r] = -1e30f;
            }
        }

        // in-lane max over 16 + one cross-half shfl
        float t0 = fmaxf(s[0], s[1]),   t1 = fmaxf(s[2], s[3]);
        float t2 = fmaxf(s[4], s[5]),   t3 = fmaxf(s[6], s[7]);
        float t4 = fmaxf(s[8], s[9]),   t5 = fmaxf(s[10], s[11]);
        float t6 = fmaxf(s[12], s[13]), t7 = fmaxf(s[14], s[15]);
        t0 = fmaxf(t0, t1); t2 = fmaxf(t2, t3); t4 = fmaxf(t4, t5); t6 = fmaxf(t6, t7);
        float tmax = fmaxf(fmaxf(t0, t2), fmaxf(t4, t6));
        tmax = fmaxf(tmax, __shfl_xor(tmax, 32));

        float corr = 1.f;
        if (!__all(tmax <= m)) {          // skip-rescale: exact when max didn't grow
            float mnew = fmaxf(m, tmax);
            corr = __expf(m - mnew);
            m = mnew;
            ot0 *= corr;
            ot1 *= corr;
        }

        float pe[16];
        float rs = 0.f;
#pragma unroll
        for (int r = 0; r < 16; r++) { pe[r] = __expf(s[r] - m); rs += pe[r]; }
        rs += __shfl_xor(rs, 32);
        l = l * corr + rs;

        // P -> LDS (bf16, swizzled+padded) -> B-frag for PV
#pragma unroll
        for (int rp = 0; rp < 8; rp++) {
            const int r = rp * 2;
            const int kv = ((r & 3) + 8 * (r >> 2)) + 4 * hi;   // even
            *(uint32_t*)(pw + ql * PSTRIDE + (kv ^ swz)) = pack2(pe[r], pe[r + 1]);
        }
        bf16x8 pa0 = *(const bf16x8*)(pw + ql * PSTRIDE + ((hi * 8) ^ swz));
        bf16x8 pa1 = *(const bf16x8*)(pw + ql * PSTRIDE + ((16 + hi * 8) ^ swz));

        // O^T[d][q] += V^T · P^T
        ot0 = MFMA32(va[0], pa0, ot0);
        ot0 = MFMA32(va[1], pa1, ot0);
        ot1 = MFMA32(va[2], pa0, ot1);
        ot1 = MFMA32(va[3], pa1, ot1);
    }

    // epilogue: normalize, write attn output [B,S,H*64] bf16 (paired u32 stores)
    const float inv = 1.f / l;
    const int b = bh >> 4, hh = bh & 15;
    u16* orow = Og + ((size_t)(b * S_LEN) + qbase + ql) * D_DIM + hh * 64;
#pragma unroll
    for (int rp = 0; rp < 8; rp++) {
        const int r = rp * 2;
        const int d = ((r & 3) + 8 * (r >> 2)) + 4 * hi;
        *(uint32_t*)(orow + d) = pack2(ot0[r] * inv, ot0[r + 1] * inv);
        *(uint32_t*)(orow + 32 + d) = pack2(ot1[r] * inv, ot1[r + 1] * inv);
    }
}

// ---------------- launch ----------------

extern "C" void kernel_launch(void* const* d_in, const int* in_sizes, int n_in,
                              void* d_out, int out_size, void* d_ws, size_t ws_size,
                              hipStream_t stream) {
    const float* x  = (const float*)d_in[0];   // [2,2048,1024]
    const float* w1 = (const float*)d_in[1];   // [1024,3072]
    const float* b1 = (const float*)d_in[2];   // [3072]
    const float* w2 = (const float*)d_in[3];   // [1024,1024]
    const float* b2 = (const float*)d_in[4];   // [1024]
    float* out = (float*)d_out;                // [2,2048,1024] f32

    u16* ws  = (u16*)d_ws;
    u16* xb  = ws;                       // 4096*1024
    u16* w1t = xb  + 4096 * 1024;        // 3072*1024  (= c_attn_w^T)
    u16* w2t = w1t + 3072 * 1024;        // 1024*1024  (= c_proj_w^T)
    u16* q   = w2t + 1024 * 1024;        // [B,H,S,64]
    u16* k   = q   + 4194304;            // [B,H,S,64]
    u16* vt  = k   + 4194304;            // [B,H,64,S]
    u16* x2  = vt  + 4194304;            // attn out bf16 [4096,1024]

    cvt_bf16_kernel<<<dim3(4096), dim3(256), 0, stream>>>(x, xb, 4096 * 1024);
    transpose_cvt_kernel<<<dim3(3072 / 32, 1024 / 32), dim3(256), 0, stream>>>(w1, w1t, 1024, 3072);
    transpose_cvt_kernel<<<dim3(1024 / 32, 1024 / 32), dim3(256), 0, stream>>>(w2, w2t, 1024, 1024);

    gemm_bt_kernel<1><<<dim3(3072 / 128, 4096 / 128), dim3(256), 0, stream>>>(
        xb, w1t, b1, nullptr, q, k, vt, 4096, 3072, 1024);

    flash_attn_kernel<<<dim3(512), dim3(256), 0, stream>>>(q, k, vt, x2);

    gemm_bt_kernel<0><<<dim3(1024 / 128, 4096 / 128), dim3(256), 0, stream>>>(
        x2, w2t, b2, out, nullptr, nullptr, nullptr, 4096, 1024, 1024);
}

// Round 4
// 235.056 us; speedup vs baseline: 1.6515x; 1.0005x over previous
//
#include <hip/hip_runtime.h>
#include <hip/hip_bf16.h>
#include <stdint.h>

// Problem constants: B=2, S=2048, D=1024, H=16, HD=64
#define S_LEN 2048
#define D_DIM 1024
#define N_HEAD 16

typedef unsigned short u16;
typedef __attribute__((ext_vector_type(4))) float f32x4;
typedef __attribute__((ext_vector_type(16))) float f32x16;
typedef __attribute__((ext_vector_type(8))) short bf16x8;   // 8 bf16 = 4 VGPRs (MFMA A/B frag)
typedef __attribute__((ext_vector_type(4))) unsigned short u16x4;
typedef __attribute__((ext_vector_type(4))) float flt4;

#define MFMA16(a, b, c) __builtin_amdgcn_mfma_f32_16x16x32_bf16((a), (b), (c), 0, 0, 0)
#define MFMA32(a, b, c) __builtin_amdgcn_mfma_f32_32x32x16_bf16((a), (b), (c), 0, 0, 0)

__device__ __forceinline__ u16 f32_bf16(float f) {
    union { float f; uint32_t u; } x;
    x.f = f;
    uint32_t r = (x.u + 0x7FFFu + ((x.u >> 16) & 1u)) >> 16;  // RNE
    return (u16)r;
}

__device__ __forceinline__ uint32_t pack2(float a, float b) {
    __hip_bfloat162 h = __float22bfloat162_rn(float2{a, b});
    return *(uint32_t*)&h;
}

// async global->LDS, 16B per lane. LDS dest = wave-uniform base + lane*16.
__device__ __forceinline__ void gload_lds16(const void* g, void* l) {
    __builtin_amdgcn_global_load_lds(
        (const __attribute__((address_space(1))) unsigned int*)(uintptr_t)g,
        (__attribute__((address_space(3))) unsigned int*)(uint32_t)(uintptr_t)l,
        16, 0, 0);
}

// ---------------- conversion kernels ----------------

__global__ __launch_bounds__(256) void cvt_bf16_kernel(const float* __restrict__ in,
                                                       u16* __restrict__ out, int n) {
    int i = (blockIdx.x * 256 + threadIdx.x) * 4;
    if (i < n) {
        flt4 v = *(const flt4*)(in + i);
        u16x4 u;
        u[0] = f32_bf16(v[0]); u[1] = f32_bf16(v[1]);
        u[2] = f32_bf16(v[2]); u[3] = f32_bf16(v[3]);
        *(u16x4*)(out + i) = u;
    }
}

// in: [R][C] f32 row-major  ->  out: [C][R] bf16 row-major (i.e. in^T)
__global__ __launch_bounds__(256) void transpose_cvt_kernel(const float* __restrict__ in,
                                                            u16* __restrict__ out,
                                                            int R, int C) {
    __shared__ float tile[32][33];
    int tc = blockIdx.x * 32, tr = blockIdx.y * 32;
    int lx = threadIdx.x & 31, ly = threadIdx.x >> 5;  // 32 x 8
#pragma unroll
    for (int i = 0; i < 32; i += 8)
        tile[ly + i][lx] = in[(size_t)(tr + ly + i) * C + tc + lx];
    __syncthreads();
#pragma unroll
    for (int i = 0; i < 32; i += 8)
        out[(size_t)(tc + ly + i) * R + tr + lx] = f32_bf16(tile[lx][ly + i]);
}

// ---------------- GEMM: C[M,N] = A[M,K] @ Bt[N,K]^T  (bf16 in, f32 acc) ----------------
// 128x128 tile, BK=32, 4 waves (2x2 of 64x64), 16x16x32 bf16 MFMA, global_load_lds staging.
// MODE 0: outF[r*N+c] = acc + bias[c]                  (f32, final projection)
// MODE 1: scatter to Q [B,H,S,64] (x 0.125*log2e), K [B,H,S,64], V^T [B,H,64,S]  (bf16)

template <int MODE>
__global__ __launch_bounds__(256)
void gemm_bt_kernel(const u16* __restrict__ A, const u16* __restrict__ Bt,
                    const float* __restrict__ bias,
                    float* __restrict__ outF,
                    u16* __restrict__ qo, u16* __restrict__ ko, u16* __restrict__ vto,
                    int M, int N, int K) {
    __shared__ u16 As[128 * 32];
    __shared__ u16 Bs[128 * 32];
    const int tid = threadIdx.x;
    const int w = tid >> 6, lane = tid & 63;
    const int lr = lane & 15, lg = lane >> 4;
    const int bm = blockIdx.y * 128, bn = blockIdx.x * 128;
    const int wr = w >> 1, wc = w & 1;

    f32x4 acc[4][4];
#pragma unroll
    for (int m = 0; m < 4; m++)
#pragma unroll
        for (int n = 0; n < 4; n++) acc[m][n] = (f32x4){0.f, 0.f, 0.f, 0.f};

    const u16* Abase = A + (size_t)(bm + (tid >> 2)) * K + (tid & 3) * 8;
    const u16* Bbase = Bt + (size_t)(bn + (tid >> 2)) * K + (tid & 3) * 8;
    u16* AsW = As + w * 512;
    u16* BsW = Bs + w * 512;

    for (int kt = 0; kt < K; kt += 32) {
        gload_lds16(Abase + kt, AsW);
        gload_lds16(Abase + kt + (size_t)64 * K, AsW + 2048);
        gload_lds16(Bbase + kt, BsW);
        gload_lds16(Bbase + kt + (size_t)64 * K, BsW + 2048);
        __syncthreads();

        bf16x8 a[4], b[4];
        const bf16x8* Av = (const bf16x8*)As;
        const bf16x8* Bv = (const bf16x8*)Bs;
#pragma unroll
        for (int m = 0; m < 4; m++) a[m] = Av[(wr * 64 + m * 16 + lr) * 4 + lg];
#pragma unroll
        for (int n = 0; n < 4; n++) b[n] = Bv[(wc * 64 + n * 16 + lr) * 4 + lg];
#pragma unroll
        for (int m = 0; m < 4; m++)
#pragma unroll
            for (int n = 0; n < 4; n++)
                acc[m][n] = MFMA16(a[m], b[n], acc[m][n]);
        __syncthreads();
    }

    const int rowb = bm + wr * 64, colb = bn + wc * 64;
    if (MODE == 0) {
#pragma unroll
        for (int m = 0; m < 4; m++)
#pragma unroll
            for (int j = 0; j < 4; j++) {
                int r = rowb + m * 16 + lg * 4 + j;
                size_t base = (size_t)r * N;
#pragma unroll
                for (int n = 0; n < 4; n++) {
                    int c = colb + n * 16 + lr;
                    outF[base + c] = acc[m][n][j] + bias[c];
                }
            }
    } else {
#pragma unroll
        for (int m = 0; m < 4; m++)
#pragma unroll
            for (int j = 0; j < 4; j++) {
                int r = rowb + m * 16 + lg * 4 + j;     // = b*S + s
                int bb = r >> 11, s = r & (S_LEN - 1);
#pragma unroll
                for (int n = 0; n < 4; n++) {
                    int c = colb + n * 16 + lr;          // 0..3D-1
                    float v = acc[m][n][j] + bias[c];
                    int part = c >> 10, cc = c & (D_DIM - 1);
                    // fold 1/sqrt(64) * log2(e) into Q  (flash works in exp2 domain)
                    if (part == 0) v *= 0.125f * 1.44269504f;
                    u16 bv = f32_bf16(v);
                    int h = cc >> 6, d = cc & 63;
                    size_t bh = (size_t)(bb * N_HEAD + h);
                    if (part == 0)      qo[(bh * S_LEN + s) * 64 + d] = bv;
                    else if (part == 1) ko[(bh * S_LEN + s) * 64 + d] = bv;
                    else                vto[(bh * 64 + d) * S_LEN + s] = bv;
                }
            }
    }
}

// ---------------- flash attention (causal), 32x32x16 MFMA, swapped QK^T ----------------
// 2048 one-wave blocks (64 thr). id -> (bh = id&31, qt = 63 - id>>5): id%8 == bh%8 keeps
// each head's blocks on one XCD (KV L2-resident), and qt descends over dispatch order
// (LPT: longest blocks first -> self-balancing packing). Per wave: 32 q-rows, kv tiles
// of 32, K/V register double-buffered, softmax fully in-lane (S^T: lane = q-column),
// P re-layout accum->B-frag via cvt_pk + permlane32_swap (no LDS at all).

__global__ __launch_bounds__(64)
void flash_attn_kernel(const u16* __restrict__ Qg, const u16* __restrict__ Kg,
                       const u16* __restrict__ Vt, u16* __restrict__ Og) {
    const int id = blockIdx.x;
    const int bh = id & 31;              // id%8 = bh%8 -> 4 heads per XCD
    const int qt = 63 - (id >> 5);       // descending work (LPT)
    const int qbase = qt * 32;
    const int lane = threadIdx.x;
    const int ql = lane & 31, hi = lane >> 5;

    const u16* Qh = Qg + (size_t)bh * S_LEN * 64;
    const u16* Kh = Kg + (size_t)bh * S_LEN * 64;
    const u16* Vh = Vt + (size_t)bh * 64 * S_LEN;

    // Q B-frag (col=q=ql, k=d): 4 chunks of K=16 (pre-scaled by 0.125*log2e in GEMM1)
    bf16x8 qf[4];
#pragma unroll
    for (int c = 0; c < 4; c++)
        qf[c] = *(const bf16x8*)(Qh + (size_t)(qbase + ql) * 64 + c * 16 + hi * 8);

    f32x16 ot0 = {}, ot1 = {};   // O^T accum: col=q, rows d 0..31 / 32..63
    float m = -1e30f, l = 0.f;

    // prefetch tile 0: K A-frag rows kv=ql, k=d; V^T A-frag rows d, k=kv
    bf16x8 kn[4], vn[4];
#pragma unroll
    for (int c = 0; c < 4; c++)
        kn[c] = *(const bf16x8*)(Kh + (size_t)ql * 64 + c * 16 + hi * 8);
#pragma unroll
    for (int u = 0; u < 4; u++)
        vn[u] = *(const bf16x8*)(Vh + (size_t)((u >> 1) * 32 + ql) * S_LEN + (u & 1) * 16 + hi * 8);

    for (int t = 0; t <= qt; ++t) {
        bf16x8 ka[4] = {kn[0], kn[1], kn[2], kn[3]};
        bf16x8 va[4] = {vn[0], vn[1], vn[2], vn[3]};
        if (t < qt) {   // issue next-tile loads now; latency hides under compute
            const size_t kvn = (size_t)(t + 1) * 32;
#pragma unroll
            for (int c = 0; c < 4; c++)
                kn[c] = *(const bf16x8*)(Kh + (kvn + ql) * 64 + c * 16 + hi * 8);
#pragma unroll
            for (int u = 0; u < 4; u++)
                vn[u] = *(const bf16x8*)(Vh + (size_t)((u >> 1) * 32 + ql) * S_LEN + kvn + (u & 1) * 16 + hi * 8);
        }

        // S^T[kv][q] = K·Q : lane holds 16 kv for q=ql  (log2 domain)
        f32x16 st = {};
        __builtin_amdgcn_s_setprio(1);
#pragma unroll
        for (int c = 0; c < 4; c++) st = MFMA32(ka[c], qf[c], st);
        __builtin_amdgcn_s_setprio(0);

        float s[16];
#pragma unroll
        for (int r = 0; r < 16; r++) s[r] = st[r];
        if (t == qt) {  // only the diagonal tile needs the causal mask
#pragma unroll
            for (int r = 0; r < 16; r++) {
                int kvl = ((r & 3) + 8 * (r >> 2)) + 4 * hi;
                if (kvl > ql) s[r] = -1e30f;
            }
        }

        // in-lane max over 16 + one cross-half shfl
        float t0 = fmaxf(s[0], s[1]),   t1 = fmaxf(s[2], s[3]);
        float t2 = fmaxf(s[4], s[5]),   t3 = fmaxf(s[6], s[7]);
        float t4 = fmaxf(s[8], s[9]),   t5 = fmaxf(s[10], s[11]);
        float t6 = fmaxf(s[12], s[13]), t7 = fmaxf(s[14], s[15]);
        t0 = fmaxf(t0, t1); t2 = fmaxf(t2, t3); t4 = fmaxf(t4, t5); t6 = fmaxf(t6, t7);
        float tmax = fmaxf(fmaxf(t0, t2), fmaxf(t4, t6));
        tmax = fmaxf(tmax, __shfl_xor(tmax, 32));

        float corr = 1.f;
        if (!__all(tmax <= m)) {          // skip-rescale: exact when max didn't grow
            float mnew = fmaxf(m, tmax);
            corr = __builtin_amdgcn_exp2f(m - mnew);
            m = mnew;
            ot0 *= corr;
            ot1 *= corr;
        }

        float pe[16];
        float rs = 0.f;
#pragma unroll
        for (int r = 0; r < 16; r++) { pe[r] = __builtin_amdgcn_exp2f(s[r] - m); rs += pe[r]; }
        rs += __shfl_xor(rs, 32);
        l = l * corr + rs;

        // P accum-layout -> B-frag, fully in-register:
        // word s holds kv pair; own kv words {4h,4h+2, 8+4h,10+4h, 16+4h,18+4h, 24+4h,26+4h};
        // permlane32_swap(w0,w2)->pa0 words{0,2}, (w1,w3)->pa0{1,3}, (w4,w6)/(w5,w7)->pa1.
        uint32_t wv[8];
#pragma unroll
        for (int sp = 0; sp < 8; sp++) wv[sp] = pack2(pe[2 * sp], pe[2 * sp + 1]);
        auto r02 = __builtin_amdgcn_permlane32_swap(wv[0], wv[2], false, false);
        auto r13 = __builtin_amdgcn_permlane32_swap(wv[1], wv[3], false, false);
        auto r46 = __builtin_amdgcn_permlane32_swap(wv[4], wv[6], false, false);
        auto r57 = __builtin_amdgcn_permlane32_swap(wv[5], wv[7], false, false);
        union { uint32_t u[4]; bf16x8 v; } pa0, pa1;
        pa0.u[0] = r02[0]; pa0.u[1] = r13[0]; pa0.u[2] = r02[1]; pa0.u[3] = r13[1];
        pa1.u[0] = r46[0]; pa1.u[1] = r57[0]; pa1.u[2] = r46[1]; pa1.u[3] = r57[1];

        // O^T[d][q] += V^T · P^T
        __builtin_amdgcn_s_setprio(1);
        ot0 = MFMA32(va[0], pa0.v, ot0);
        ot0 = MFMA32(va[1], pa1.v, ot0);
        ot1 = MFMA32(va[2], pa0.v, ot1);
        ot1 = MFMA32(va[3], pa1.v, ot1);
        __builtin_amdgcn_s_setprio(0);
    }

    // epilogue: normalize, write attn output [B,S,H*64] bf16 (paired u32 stores)
    const float inv = 1.f / l;
    const int b = bh >> 4, hh = bh & 15;
    u16* orow = Og + ((size_t)(b * S_LEN) + qbase + ql) * D_DIM + hh * 64;
#pragma unroll
    for (int rp = 0; rp < 8; rp++) {
        const int r = rp * 2;
        const int d = ((r & 3) + 8 * (r >> 2)) + 4 * hi;
        *(uint32_t*)(orow + d) = pack2(ot0[r] * inv, ot0[r + 1] * inv);
        *(uint32_t*)(orow + 32 + d) = pack2(ot1[r] * inv, ot1[r + 1] * inv);
    }
}

// ---------------- launch ----------------

extern "C" void kernel_launch(void* const* d_in, const int* in_sizes, int n_in,
                              void* d_out, int out_size, void* d_ws, size_t ws_size,
                              hipStream_t stream) {
    const float* x  = (const float*)d_in[0];   // [2,2048,1024]
    const float* w1 = (const float*)d_in[1];   // [1024,3072]
    const float* b1 = (const float*)d_in[2];   // [3072]
    const float* w2 = (const float*)d_in[3];   // [1024,1024]
    const float* b2 = (const float*)d_in[4];   // [1024]
    float* out = (float*)d_out;                // [2,2048,1024] f32

    u16* ws  = (u16*)d_ws;
    u16* xb  = ws;                       // 4096*1024
    u16* w1t = xb  + 4096 * 1024;        // 3072*1024  (= c_attn_w^T)
    u16* w2t = w1t + 3072 * 1024;        // 1024*1024  (= c_proj_w^T)
    u16* q   = w2t + 1024 * 1024;        // [B,H,S,64]
    u16* k   = q   + 4194304;            // [B,H,S,64]
    u16* vt  = k   + 4194304;            // [B,H,64,S]
    u16* x2  = vt  + 4194304;            // attn out bf16 [4096,1024]

    cvt_bf16_kernel<<<dim3(4096), dim3(256), 0, stream>>>(x, xb, 4096 * 1024);
    transpose_cvt_kernel<<<dim3(3072 / 32, 1024 / 32), dim3(256), 0, stream>>>(w1, w1t, 1024, 3072);
    transpose_cvt_kernel<<<dim3(1024 / 32, 1024 / 32), dim3(256), 0, stream>>>(w2, w2t, 1024, 1024);

    gemm_bt_kernel<1><<<dim3(3072 / 128, 4096 / 128), dim3(256), 0, stream>>>(
        xb, w1t, b1, nullptr, q, k, vt, 4096, 3072, 1024);

    flash_attn_kernel<<<dim3(2048), dim3(64), 0, stream>>>(q, k, vt, x2);

    gemm_bt_kernel<0><<<dim3(1024 / 128, 4096 / 128), dim3(256), 0, stream>>>(
        x2, w2t, b2, out, nullptr, nullptr, nullptr, 4096, 1024, 1024);
}

// Round 6
// 218.548 us; speedup vs baseline: 1.7762x; 1.0755x over previous
//
#include <hip/hip_runtime.h>
#include <hip/hip_bf16.h>
#include <stdint.h>

// Problem constants: B=2, S=2048, D=1024, H=16, HD=64
#define S_LEN 2048
#define D_DIM 1024
#define N_HEAD 16

typedef unsigned short u16;
typedef __attribute__((ext_vector_type(4))) float f32x4;
typedef __attribute__((ext_vector_type(16))) float f32x16;
typedef __attribute__((ext_vector_type(8))) short bf16x8;   // 8 bf16 = 4 VGPRs (MFMA A/B frag)
typedef __attribute__((ext_vector_type(4))) unsigned short u16x4;
typedef __attribute__((ext_vector_type(4))) float flt4;

#define MFMA16(a, b, c) __builtin_amdgcn_mfma_f32_16x16x32_bf16((a), (b), (c), 0, 0, 0)
#define MFMA32(a, b, c) __builtin_amdgcn_mfma_f32_32x32x16_bf16((a), (b), (c), 0, 0, 0)

__device__ __forceinline__ u16 f32_bf16(float f) {
    union { float f; uint32_t u; } x;
    x.f = f;
    uint32_t r = (x.u + 0x7FFFu + ((x.u >> 16) & 1u)) >> 16;  // RNE
    return (u16)r;
}

__device__ __forceinline__ uint32_t pack2(float a, float b) {
    __hip_bfloat162 h = __float22bfloat162_rn(float2{a, b});
    return *(uint32_t*)&h;
}

// async global->LDS, 16B per lane. LDS dest = wave-uniform base + lane*16.
__device__ __forceinline__ void gload_lds16(const void* g, void* l) {
    __builtin_amdgcn_global_load_lds(
        (const __attribute__((address_space(1))) unsigned int*)(uintptr_t)g,
        (__attribute__((address_space(3))) unsigned int*)(uint32_t)(uintptr_t)l,
        16, 0, 0);
}

// ---------------- conversion kernels ----------------

__global__ __launch_bounds__(256) void cvt_bf16_kernel(const float* __restrict__ in,
                                                       u16* __restrict__ out, int n) {
    int i = (blockIdx.x * 256 + threadIdx.x) * 4;
    if (i < n) {
        flt4 v = *(const flt4*)(in + i);
        u16x4 u;
        u[0] = f32_bf16(v[0]); u[1] = f32_bf16(v[1]);
        u[2] = f32_bf16(v[2]); u[3] = f32_bf16(v[3]);
        *(u16x4*)(out + i) = u;
    }
}

// in: [R][C] f32 row-major  ->  out: [C][R] bf16 row-major (i.e. in^T)
__global__ __launch_bounds__(256) void transpose_cvt_kernel(const float* __restrict__ in,
                                                            u16* __restrict__ out,
                                                            int R, int C) {
    __shared__ float tile[32][33];
    int tc = blockIdx.x * 32, tr = blockIdx.y * 32;
    int lx = threadIdx.x & 31, ly = threadIdx.x >> 5;  // 32 x 8
#pragma unroll
    for (int i = 0; i < 32; i += 8)
        tile[ly + i][lx] = in[(size_t)(tr + ly + i) * C + tc + lx];
    __syncthreads();
#pragma unroll
    for (int i = 0; i < 32; i += 8)
        out[(size_t)(tc + ly + i) * R + tr + lx] = f32_bf16(tile[lx][ly + i]);
}

// ---------------- GEMM: C[M,N] = A[M,K] @ Bt[N,K]^T  (bf16 in, f32 acc) ----------------
// 128x128 tile, BK=32, 4 waves (2x2 of 64x64), 16x16x32 bf16 MFMA, global_load_lds staging.
// MODE 0: outF[r*N+c] = acc + bias[c]                  (f32, final projection)
// MODE 1: scatter to Q [B,H,S,64] (x 0.125*log2e), K [B,H,S,64], V^T [B,H,64,S]  (bf16)

template <int MODE>
__global__ __launch_bounds__(256)
void gemm_bt_kernel(const u16* __restrict__ A, const u16* __restrict__ Bt,
                    const float* __restrict__ bias,
                    float* __restrict__ outF,
                    u16* __restrict__ qo, u16* __restrict__ ko, u16* __restrict__ vto,
                    int M, int N, int K) {
    __shared__ u16 As[128 * 32];
    __shared__ u16 Bs[128 * 32];
    const int tid = threadIdx.x;
    const int w = tid >> 6, lane = tid & 63;
    const int lr = lane & 15, lg = lane >> 4;
    const int bm = blockIdx.y * 128, bn = blockIdx.x * 128;
    const int wr = w >> 1, wc = w & 1;

    f32x4 acc[4][4];
#pragma unroll
    for (int m = 0; m < 4; m++)
#pragma unroll
        for (int n = 0; n < 4; n++) acc[m][n] = (f32x4){0.f, 0.f, 0.f, 0.f};

    const u16* Abase = A + (size_t)(bm + (tid >> 2)) * K + (tid & 3) * 8;
    const u16* Bbase = Bt + (size_t)(bn + (tid >> 2)) * K + (tid & 3) * 8;
    u16* AsW = As + w * 512;
    u16* BsW = Bs + w * 512;

    for (int kt = 0; kt < K; kt += 32) {
        gload_lds16(Abase + kt, AsW);
        gload_lds16(Abase + kt + (size_t)64 * K, AsW + 2048);
        gload_lds16(Bbase + kt, BsW);
        gload_lds16(Bbase + kt + (size_t)64 * K, BsW + 2048);
        __syncthreads();

        bf16x8 a[4], b[4];
        const bf16x8* Av = (const bf16x8*)As;
        const bf16x8* Bv = (const bf16x8*)Bs;
#pragma unroll
        for (int m = 0; m < 4; m++) a[m] = Av[(wr * 64 + m * 16 + lr) * 4 + lg];
#pragma unroll
        for (int n = 0; n < 4; n++) b[n] = Bv[(wc * 64 + n * 16 + lr) * 4 + lg];
#pragma unroll
        for (int m = 0; m < 4; m++)
#pragma unroll
            for (int n = 0; n < 4; n++)
                acc[m][n] = MFMA16(a[m], b[n], acc[m][n]);
        __syncthreads();
    }

    const int rowb = bm + wr * 64, colb = bn + wc * 64;
    if (MODE == 0) {
#pragma unroll
        for (int m = 0; m < 4; m++)
#pragma unroll
            for (int j = 0; j < 4; j++) {
                int r = rowb + m * 16 + lg * 4 + j;
                size_t base = (size_t)r * N;
#pragma unroll
                for (int n = 0; n < 4; n++) {
                    int c = colb + n * 16 + lr;
                    outF[base + c] = acc[m][n][j] + bias[c];
                }
            }
    } else {
#pragma unroll
        for (int m = 0; m < 4; m++)
#pragma unroll
            for (int j = 0; j < 4; j++) {
                int r = rowb + m * 16 + lg * 4 + j;     // = b*S + s
                int bb = r >> 11, s = r & (S_LEN - 1);
#pragma unroll
                for (int n = 0; n < 4; n++) {
                    int c = colb + n * 16 + lr;          // 0..3D-1
                    float v = acc[m][n][j] + bias[c];
                    int part = c >> 10, cc = c & (D_DIM - 1);
                    // fold 1/sqrt(64) * log2(e) into Q  (flash works in exp2 domain)
                    if (part == 0) v *= 0.125f * 1.44269504f;
                    u16 bv = f32_bf16(v);
                    int h = cc >> 6, d = cc & 63;
                    size_t bh = (size_t)(bb * N_HEAD + h);
                    if (part == 0)      qo[(bh * S_LEN + s) * 64 + d] = bv;
                    else if (part == 1) ko[(bh * S_LEN + s) * 64 + d] = bv;
                    else                vto[(bh * 64 + d) * S_LEN + s] = bv;
                }
            }
    }
}

// ---------------- flash attention (causal), paired q-tiles + kv parity split ----------------
// 1024 blocks x 128 thr (2 waves). Block -> (bh = id&31 [XCD-local heads], p = id>>5, 0..31).
// Both waves serve q-tile pair A = p, B = 63-p (same kv tiles -> shared K/V loads; total
// compute = 65 tile-units/wave pair -> perfectly uniform grid, 8 waves/CU resident).
// Wave w processes kv tiles t = w, w+2, ... (parity split); partials merged via LDS
// (LSE merge) at the end. Softmax fully in-lane (S^T: lane = q-col, swapped QK^T);
// P relayout accum->B-frag via cvt_pk + permlane32_swap; K/V ping-pong double-buffered.

__global__ __launch_bounds__(128, 2)
void flash_attn_kernel(const u16* __restrict__ Qg, const u16* __restrict__ Kg,
                       const u16* __restrict__ Vt, u16* __restrict__ Og) {
    const int id = blockIdx.x;
    const int bh = id & 31;              // id%8 = bh%8 -> 4 heads per XCD (KV L2-resident)
    const int p  = id >> 5;              // 0..31
    const int w = threadIdx.x >> 6;      // kv parity
    const int lane = threadIdx.x & 63;
    const int ql = lane & 31, hi = lane >> 5;
    const int qbA = p * 32, qbB = (63 - p) * 32;
    const int last = 63 - p;             // B's diagonal tile index (>= 32 > p always)

    const u16* Qh = Qg + (size_t)bh * S_LEN * 64;
    const u16* Kh = Kg + (size_t)bh * S_LEN * 64;
    const u16* Vh = Vt + (size_t)bh * 64 * S_LEN;

    __shared__ float mbuf[2][64][34];    // wave1 partials: m, l, ot0[16], ot1[16]

    // Q B-frags (col=q=ql, k=d), pre-scaled by 0.125*log2e in GEMM1
    bf16x8 qfA[4], qfB[4];
#pragma unroll
    for (int c = 0; c < 4; c++) {
        qfA[c] = *(const bf16x8*)(Qh + (size_t)(qbA + ql) * 64 + c * 16 + hi * 8);
        qfB[c] = *(const bf16x8*)(Qh + (size_t)(qbB + ql) * 64 + c * 16 + hi * 8);
    }

    f32x16 otA0 = {}, otA1 = {}, otB0 = {}, otB1 = {};
    float mA = -1e30f, lA = 0.f, mB = -1e30f, lB = 0.f;

    auto loadKV = [&](int t, bf16x8 (&k)[4], bf16x8 (&v)[4]) {
        const u16* kp = Kh + ((size_t)t * 32 + ql) * 64 + hi * 8;
#pragma unroll
        for (int c = 0; c < 4; c++) k[c] = *(const bf16x8*)(kp + c * 16);
        const size_t kv0 = (size_t)t * 32;
#pragma unroll
        for (int u = 0; u < 4; u++)
            v[u] = *(const bf16x8*)(Vh + ((size_t)((u >> 1) * 32 + ql)) * S_LEN + kv0 + (u & 1) * 16 + hi * 8);
    };

    // softmax + PV for one q-tile's S^T column (lane = q), online, exp2 domain
    auto softpv = [&](const f32x16& st, bool diag, float& m, float& l,
                      f32x16& o0, f32x16& o1, const bf16x8 (&v)[4]) {
        float s[16];
#pragma unroll
        for (int r = 0; r < 16; r++) s[r] = st[r];
        if (diag) {
#pragma unroll
            for (int r = 0; r < 16; r++) {
                int kvl = ((r & 3) + 8 * (r >> 2)) + 4 * hi;
                if (kvl > ql) s[r] = -1e30f;
            }
        }
        float t0 = fmaxf(s[0], s[1]),   t1 = fmaxf(s[2], s[3]);
        float t2 = fmaxf(s[4], s[5]),   t3 = fmaxf(s[6], s[7]);
        float t4 = fmaxf(s[8], s[9]),   t5 = fmaxf(s[10], s[11]);
        float t6 = fmaxf(s[12], s[13]), t7 = fmaxf(s[14], s[15]);
        t0 = fmaxf(t0, t1); t2 = fmaxf(t2, t3); t4 = fmaxf(t4, t5); t6 = fmaxf(t6, t7);
        float tmax = fmaxf(fmaxf(t0, t2), fmaxf(t4, t6));
        tmax = fmaxf(tmax, __shfl_xor(tmax, 32));

        float corr = 1.f;
        if (!__all(tmax <= m)) {          // skip-rescale when max didn't grow
            float mn = fmaxf(m, tmax);
            corr = __builtin_amdgcn_exp2f(m - mn);
            m = mn;
            o0 *= corr;
            o1 *= corr;
        }
        float pe[16];
        float rs = 0.f;
#pragma unroll
        for (int r = 0; r < 16; r++) { pe[r] = __builtin_amdgcn_exp2f(s[r] - m); rs += pe[r]; }
        rs += __shfl_xor(rs, 32);
        l = l * corr + rs;

        // P accum-layout -> B-frag in-register (verified R4): cvt_pk + permlane32_swap
        uint32_t wv[8];
#pragma unroll
        for (int sp = 0; sp < 8; sp++) wv[sp] = pack2(pe[2 * sp], pe[2 * sp + 1]);
        auto r02 = __builtin_amdgcn_permlane32_swap(wv[0], wv[2], false, false);
        auto r13 = __builtin_amdgcn_permlane32_swap(wv[1], wv[3], false, false);
        auto r46 = __builtin_amdgcn_permlane32_swap(wv[4], wv[6], false, false);
        auto r57 = __builtin_amdgcn_permlane32_swap(wv[5], wv[7], false, false);
        union { uint32_t u[4]; bf16x8 v; } pa0, pa1;
        pa0.u[0] = r02[0]; pa0.u[1] = r13[0]; pa0.u[2] = r02[1]; pa0.u[3] = r13[1];
        pa1.u[0] = r46[0]; pa1.u[1] = r57[0]; pa1.u[2] = r46[1]; pa1.u[3] = r57[1];

        __builtin_amdgcn_s_setprio(1);
        o0 = MFMA32(v[0], pa0.v, o0);
        o0 = MFMA32(v[1], pa1.v, o0);
        o1 = MFMA32(v[2], pa0.v, o1);
        o1 = MFMA32(v[3], pa1.v, o1);
        __builtin_amdgcn_s_setprio(0);
    };

    auto step = [&](int t, const bf16x8 (&k)[4], const bf16x8 (&v)[4]) {
        const bool actA = (t <= p);
        f32x16 stA = {}, stB = {};
        __builtin_amdgcn_s_setprio(1);
        if (actA) {
#pragma unroll
            for (int c = 0; c < 4; c++) stA = MFMA32(k[c], qfA[c], stA);
        }
#pragma unroll
        for (int c = 0; c < 4; c++) stB = MFMA32(k[c], qfB[c], stB);
        __builtin_amdgcn_s_setprio(0);
        if (actA) softpv(stA, t == p, mA, lA, otA0, otA1, v);
        softpv(stB, t == last, mB, lB, otB0, otB1, v);
    };

    // ping-pong K/V double buffer, unroll-2 (static register assignment, no copies)
    bf16x8 k0[4], v0[4], k1[4], v1[4];
    loadKV(w, k0, v0);
    int t = w;
    for (;;) {
        if (t + 2 <= last) loadKV(t + 2, k1, v1);
        step(t, k0, v0);
        t += 2;
        if (t > last) break;
        if (t + 2 <= last) loadKV(t + 2, k0, v0);
        step(t, k1, v1);
        t += 2;
        if (t > last) break;
    }

    // merge wave partials (LSE merge) and write [B,S,H*64] bf16
    if (w == 1) {
        float* bA = mbuf[0][lane];
        float* bB = mbuf[1][lane];
        bA[0] = mA; bA[1] = lA;
        bB[0] = mB; bB[1] = lB;
#pragma unroll
        for (int r = 0; r < 16; r++) {
            bA[2 + r] = otA0[r]; bA[18 + r] = otA1[r];
            bB[2 + r] = otB0[r]; bB[18 + r] = otB1[r];
        }
    }
    __syncthreads();
    if (w == 0) {
        const int bb = bh >> 4, hh = bh & 15;
        auto fin = [&](float m0, float l0, const f32x16& o0, const f32x16& o1,
                       const float* b, int qbase) {
            float m1 = b[0], l1 = b[1];
            float ms = fmaxf(m0, m1);
            float a0 = __builtin_amdgcn_exp2f(m0 - ms);
            float a1 = __builtin_amdgcn_exp2f(m1 - ms);
            float inv = 1.f / (l0 * a0 + l1 * a1);
            u16* orow = Og + ((size_t)(bb * S_LEN) + qbase + ql) * D_DIM + hh * 64;
#pragma unroll
            for (int rp = 0; rp < 8; rp++) {
                int r = rp * 2;
                int d = ((r & 3) + 8 * (r >> 2)) + 4 * hi;
                float x0 = (o0[r] * a0 + b[2 + r] * a1) * inv;
                float x1 = (o0[r + 1] * a0 + b[2 + r + 1] * a1) * inv;
                *(uint32_t*)(orow + d) = pack2(x0, x1);
                float y0 = (o1[r] * a0 + b[18 + r] * a1) * inv;
                float y1 = (o1[r + 1] * a0 + b[18 + r + 1] * a1) * inv;
                *(uint32_t*)(orow + 32 + d) = pack2(y0, y1);
            }
        };
        fin(mA, lA, otA0, otA1, mbuf[0][lane], qbA);
        fin(mB, lB, otB0, otB1, mbuf[1][lane], qbB);
    }
}

// ---------------- launch ----------------

extern "C" void kernel_launch(void* const* d_in, const int* in_sizes, int n_in,
                              void* d_out, int out_size, void* d_ws, size_t ws_size,
                              hipStream_t stream) {
    const float* x  = (const float*)d_in[0];   // [2,2048,1024]
    const float* w1 = (const float*)d_in[1];   // [1024,3072]
    const float* b1 = (const float*)d_in[2];   // [3072]
    const float* w2 = (const float*)d_in[3];   // [1024,1024]
    const float* b2 = (const float*)d_in[4];   // [1024]
    float* out = (float*)d_out;                // [2,2048,1024] f32

    u16* ws  = (u16*)d_ws;
    u16* xb  = ws;                       // 4096*1024
    u16* w1t = xb  + 4096 * 1024;        // 3072*1024  (= c_attn_w^T)
    u16* w2t = w1t + 3072 * 1024;        // 1024*1024  (= c_proj_w^T)
    u16* q   = w2t + 1024 * 1024;        // [B,H,S,64]
    u16* k   = q   + 4194304;            // [B,H,S,64]
    u16* vt  = k   + 4194304;            // [B,H,64,S]
    u16* x2  = vt  + 4194304;            // attn out bf16 [4096,1024]

    cvt_bf16_kernel<<<dim3(4096), dim3(256), 0, stream>>>(x, xb, 4096 * 1024);
    transpose_cvt_kernel<<<dim3(3072 / 32, 1024 / 32), dim3(256), 0, stream>>>(w1, w1t, 1024, 3072);
    transpose_cvt_kernel<<<dim3(1024 / 32, 1024 / 32), dim3(256), 0, stream>>>(w2, w2t, 1024, 1024);

    gemm_bt_kernel<1><<<dim3(3072 / 128, 4096 / 128), dim3(256), 0, stream>>>(
        xb, w1t, b1, nullptr, q, k, vt, 4096, 3072, 1024);

    flash_attn_kernel<<<dim3(1024), dim3(128), 0, stream>>>(q, k, vt, x2);

    gemm_bt_kernel<0><<<dim3(1024 / 128, 4096 / 128), dim3(256), 0, stream>>>(
        x2, w2t, b2, out, nullptr, nullptr, nullptr, 4096, 1024, 1024);
}